// Round 12
// baseline (1516.464 us; speedup 1.0000x reference)
//
#include <hip/hip_runtime.h>
#include <math.h>

// f32 I/O, f64 accumulation everywhere (bit-exact vs np-f64 ref at f32
// materialization points — absmax 0.0 R4-R11). Workspace 96 MiB:
// A(16,777,216 f32) + B(8,388,608 f32); boxes/scores in dead x1 space.
//
// R12: NO input LDS tile. Each thread reads its 4x4 window directly from
// global (L1-cached, clamped addresses + 0/1 masks — exact), with a 1-deep
// register pipeline (prefetch ci+1's 16 raws under ci's 288 FMAs). Weights
// stay in LDS, staged per CI_CHUNK=16 (2 barriers / 4608 FMA). Kills the
// staged-tile ds_write/ds_read/barrier overhead that held VALUBusy at 77%.
// Decisions locked: f32 acc REJECTED (IoU flips near-certain); Winograd-f64
// REJECTED (transform-domain acc blows the ~170-VGPR/3-wave cliff).

constexpr int TOPK_N = 200;

// ---------------------------------------------------------------------------
// Direct fused conv3x3(SAME)+bias+relu+maxpool2x2, f64 acc.
// Block = 256 threads = 16x16 pooled outputs, CO_BLK=8 out-channels/block.
// ---------------------------------------------------------------------------
template <int CIN, int CI_CHUNK, int CO_BLK>
__launch_bounds__(256)
__global__ void conv_direct(const float* __restrict__ in,
                            const float* __restrict__ wgt,
                            const float* __restrict__ bias,
                            float* __restrict__ out,
                            int Hin, int Win, int Cout) {
    constexpr int NW = CI_CHUNK * 9 * CO_BLK;
    const int Hp = Hin >> 1, Wp = Win >> 1;
    const int coChunks = Cout / CO_BLK;
    const int b  = blockIdx.z / coChunks;
    const int cz = blockIdx.z % coChunks;
    const int tid = threadIdx.x;
    const int tx = tid & 15, ty = tid >> 4;
    const int px = (blockIdx.x << 4) + tx;
    const int py = (blockIdx.y << 4) + ty;
    const int y0 = 2 * py, x0 = 2 * px;

    __shared__ double s_w[NW];

    // Clamped window row/col element offsets + 0/1 border masks (invariant).
    int rowE[4], colE[4];
    float rowM[4], colM[4];
#pragma unroll
    for (int d = 0; d < 4; ++d) {
        int iy = y0 - 1 + d;
        rowM[d] = (iy >= 0 && iy < Hin) ? 1.f : 0.f;
        iy = min(max(iy, 0), Hin - 1);
        rowE[d] = iy * Win;
        int ix = x0 - 1 + d;
        colM[d] = (ix >= 0 && ix < Win) ? 1.f : 0.f;
        colE[d] = min(max(ix, 0), Win - 1);
    }
    const size_t HW = (size_t)Hin * Win;
    const float* in_b = in + (size_t)b * CIN * HW;

    double acc[CO_BLK][4];
#pragma unroll
    for (int co = 0; co < CO_BLK; ++co)
#pragma unroll
        for (int p = 0; p < 4; ++p) acc[co][p] = 0.0;

    // Prefetch ci=0 raw window.
    float raw[16];
    {
        const float* src = in_b;
#pragma unroll
        for (int dy = 0; dy < 4; ++dy)
#pragma unroll
            for (int dx = 0; dx < 4; ++dx)
                raw[dy * 4 + dx] = src[rowE[dy] + colE[dx]];
    }

    for (int c0 = 0; c0 < CIN; c0 += CI_CHUNK) {
        __syncthreads();  // all waves done reading previous chunk's s_w
        for (int idx = tid; idx < NW; idx += 256) {
            const int co   = idx & (CO_BLK - 1);
            const int rest = idx / CO_BLK;
            const int k    = rest % 9;
            const int ciL  = rest / 9;
            s_w[idx] = (double)wgt[((cz * CO_BLK + co) * CIN + c0 + ciL) * 9 + k];
        }
        __syncthreads();

#pragma unroll 1
        for (int ciL = 0; ciL < CI_CHUNK; ++ciL) {
            const int ci = c0 + ciL;
            // widen current raws (masked) into f64 window
            double win[4][4];
#pragma unroll
            for (int dy = 0; dy < 4; ++dy)
#pragma unroll
                for (int dx = 0; dx < 4; ++dx)
                    win[dy][dx] = (double)(raw[dy * 4 + dx] * rowM[dy] * colM[dx]);
            // issue next ci's loads (land under the FMAs below)
            if (ci + 1 < CIN) {
                const float* src = in_b + (size_t)(ci + 1) * HW;
#pragma unroll
                for (int dy = 0; dy < 4; ++dy)
#pragma unroll
                    for (int dx = 0; dx < 4; ++dx)
                        raw[dy * 4 + dx] = src[rowE[dy] + colE[dx]];
            }
            // 288 f64 FMA
#pragma unroll
            for (int k = 0; k < 9; ++k) {
                const int ky = k / 3, kx = k % 3;
                const double* wp = &s_w[(ciL * 9 + k) * CO_BLK];
                double w[CO_BLK];
#pragma unroll
                for (int co = 0; co < CO_BLK; ++co) w[co] = wp[co];
#pragma unroll
                for (int p = 0; p < 4; ++p) {
                    const double v = win[(p >> 1) + ky][(p & 1) + kx];
#pragma unroll
                    for (int co = 0; co < CO_BLK; ++co)
                        acc[co][p] = fma(v, w[co], acc[co][p]);
                }
            }
        }
    }

#pragma unroll
    for (int co = 0; co < CO_BLK; ++co) {
        const double bd = (double)bias[cz * CO_BLK + co];
        const float e0 = fmaxf((float)(acc[co][0] + bd), 0.f);
        const float e1 = fmaxf((float)(acc[co][1] + bd), 0.f);
        const float e2 = fmaxf((float)(acc[co][2] + bd), 0.f);
        const float e3 = fmaxf((float)(acc[co][3] + bd), 0.f);
        out[((size_t)(b * Cout + cz * CO_BLK + co) * Hp + py) * Wp + px] =
            fmaxf(fmaxf(e0, e1), fmaxf(e2, e3));
    }
}

// ---------------------------------------------------------------------------
// Head 1x1 conv (256->5, f64) + decode (f64) -> boxes/scores. 32 blocks.
// ---------------------------------------------------------------------------
__launch_bounds__(256)
__global__ void head_decode_k(const float* __restrict__ x4,
                              const float* __restrict__ wh,
                              const float* __restrict__ bh,
                              float* __restrict__ boxes,
                              float* __restrict__ scores) {
    __shared__ float s_wh[5 * 256];
    const int tid = threadIdx.x;
#pragma unroll
    for (int i = 0; i < 5; ++i) s_wh[i * 256 + tid] = wh[i * 256 + tid];
    __syncthreads();

    const int idx  = blockIdx.x * 256 + tid;  // 0..8191
    const int b    = idx >> 10;
    const int cell = idx & 1023;
    const int gy = cell >> 5, gx = cell & 31;

    double a0 = (double)bh[0], a1 = (double)bh[1], a2 = (double)bh[2],
           a3 = (double)bh[3], a4 = (double)bh[4];
    const float* xp = x4 + b * 262144 + cell;
    for (int ci = 0; ci < 256; ++ci) {
        const double v = (double)xp[ci << 10];
        a0 = fma(v, (double)s_wh[0 * 256 + ci], a0);
        a1 = fma(v, (double)s_wh[1 * 256 + ci], a1);
        a2 = fma(v, (double)s_wh[2 * 256 + ci], a2);
        a3 = fma(v, (double)s_wh[3 * 256 + ci], a3);
        a4 = fma(v, (double)s_wh[4 * 256 + ci], a4);
    }
    const double obj = 1.0 / (1.0 + exp(-a0));
    const double txs = 1.0 / (1.0 + exp(-a1));
    const double tys = 1.0 / (1.0 + exp(-a2));
    const double bw  = exp(a3) * 16.0;
    const double bhh = exp(a4) * 16.0;
    const double cx  = gx * 16.0 + txs * 16.0;
    const double cy  = gy * 16.0 + tys * 16.0;
    float* bp = boxes + idx * 4;
    bp[0] = (float)fmin(fmax(cx - bw * 0.5, 0.0), 511.0);
    bp[1] = (float)fmin(fmax(cy - bhh * 0.5, 0.0), 511.0);
    bp[2] = (float)fmin(fmax(cx + bw * 0.5, 0.0), 511.0);
    bp[3] = (float)fmin(fmax(cy + bhh * 0.5, 0.0), 511.0);
    scores[idx] = (float)obj;
}

// ---------------------------------------------------------------------------
// Per-batch top-200 (bitonic, lax.top_k tie semantics) + greedy NMS + output.
// ---------------------------------------------------------------------------
__launch_bounds__(256)
__global__ void topk_nms_k(const float* __restrict__ boxes,
                           const float* __restrict__ scores,
                           float* __restrict__ out5,
                           float* __restrict__ keep_out) {
    const int b = blockIdx.x, tid = threadIdx.x;
    __shared__ unsigned long long key[1024];
    __shared__ float bx1[TOPK_N], by1[TOPK_N], bx2[TOPK_N], by2[TOPK_N];
    __shared__ float sv[TOPK_N], ar[TOPK_N];
    __shared__ int   kp[TOPK_N];

    for (int i = tid; i < 1024; i += 256) {
        float s = scores[b * 1024 + i];
        float m = (s >= 0.01f) ? s : -1.0f;
        unsigned u = __float_as_uint(m);
        u = (u & 0x80000000u) ? ~u : (u | 0x80000000u);
        key[i] = ((unsigned long long)u << 32) | (unsigned)(1023 - i);
    }
    __syncthreads();

    for (int k = 2; k <= 1024; k <<= 1) {
        for (int j = k >> 1; j > 0; j >>= 1) {
            for (int i = tid; i < 1024; i += 256) {
                int l = i ^ j;
                if (l > i) {
                    unsigned long long a = key[i], c = key[l];
                    bool desc = ((i & k) == 0);
                    bool sw = desc ? (a < c) : (a > c);
                    if (sw) { key[i] = c; key[l] = a; }
                }
            }
            __syncthreads();
        }
    }

    for (int i = tid; i < TOPK_N; i += 256) {
        unsigned long long kk = key[i];
        unsigned u = (unsigned)(kk >> 32);
        unsigned bits = (u & 0x80000000u) ? (u & 0x7FFFFFFFu) : ~u;
        float s = __uint_as_float(bits);
        int src = 1023 - (int)(kk & 0xFFFFFFFFu);
        const float4 bb = *(const float4*)(boxes + (b * 1024 + src) * 4);
        bx1[i] = bb.x; by1[i] = bb.y; bx2[i] = bb.z; by2[i] = bb.w;
        sv[i] = s;
        ar[i] = (bb.z - bb.x) * (bb.w - bb.y);
        kp[i] = (s >= 0.01f) ? 1 : 0;
    }
    __syncthreads();

    for (int i = 0; i < TOPK_N; ++i) {
        if (kp[i]) {
            const float X1 = bx1[i], Y1 = by1[i], X2 = bx2[i], Y2 = by2[i], A = ar[i];
            for (int j = tid; j < TOPK_N; j += 256) {
                if (j > i && kp[j]) {
                    float xx1 = fmaxf(X1, bx1[j]);
                    float yy1 = fmaxf(Y1, by1[j]);
                    float xx2 = fminf(X2, bx2[j]);
                    float yy2 = fminf(Y2, by2[j]);
                    float inter = fmaxf(xx2 - xx1, 0.f) * fmaxf(yy2 - yy1, 0.f);
                    float uni = A + ar[j] - inter;
                    float iou = inter / fmaxf(uni, 1e-6f);
                    if (iou > 0.5f) kp[j] = 0;
                }
            }
        }
        __syncthreads();
    }

    for (int i = tid; i < TOPK_N; i += 256) {
        float kf = kp[i] ? 1.f : 0.f;
        float s  = sv[i];
        float sc = (s >= 0.01f) ? s : 0.f;
        float* op = out5 + (b * TOPK_N + i) * 5;
        op[0] = bx1[i] * kf;
        op[1] = by1[i] * kf;
        op[2] = bx2[i] * kf;
        op[3] = by2[i] * kf;
        op[4] = sc * kf;
        keep_out[b * TOPK_N + i] = kf;
    }
}

extern "C" void kernel_launch(void* const* d_in, const int* in_sizes, int n_in,
                              void* d_out, int out_size, void* d_ws, size_t ws_size,
                              hipStream_t stream) {
    const float* images = (const float*)d_in[0];
    const float* w1 = (const float*)d_in[1];
    const float* b1 = (const float*)d_in[2];
    const float* w2 = (const float*)d_in[3];
    const float* b2 = (const float*)d_in[4];
    const float* w3 = (const float*)d_in[5];
    const float* b3 = (const float*)d_in[6];
    const float* w4 = (const float*)d_in[7];
    const float* b4 = (const float*)d_in[8];
    const float* wh = (const float*)d_in[9];
    const float* bh = (const float*)d_in[10];
    float* out = (float*)d_out;

    float* A    = (float*)d_ws;          // x1 [8,32,256,256] -> x3 [8,128,64,64]
    float* Bbuf = A + 16777216;          // x2 [8,64,128,128] -> x4 [8,256,32,32]
    float* boxes  = A + 8388608;         // dead x1 space: 32768 floats
    float* scores = A + 8388608 + 32768; //  8192 floats

    // L1: 3->32. 8192 blocks.
    conv_direct<3, 3, 8><<<dim3(16, 16, 8 * 4), 256, 0, stream>>>(
        images, w1, b1, A, 512, 512, 32);
    // L2: 32->64. 4096 blocks.
    conv_direct<32, 16, 8><<<dim3(8, 8, 8 * 8), 256, 0, stream>>>(
        A, w2, b2, Bbuf, 256, 256, 64);
    // L3: 64->128. 2048 blocks.
    conv_direct<64, 16, 8><<<dim3(4, 4, 8 * 16), 256, 0, stream>>>(
        Bbuf, w3, b3, A, 128, 128, 128);
    // L4: 128->256. 1024 blocks.
    conv_direct<128, 16, 8><<<dim3(2, 2, 8 * 32), 256, 0, stream>>>(
        A, w4, b4, Bbuf, 64, 64, 256);
    // Head + decode: 32 blocks, coalesced
    head_decode_k<<<32, 256, 0, stream>>>(Bbuf, wh, bh, boxes, scores);
    // Top-k + NMS + output
    topk_nms_k<<<8, 256, 0, stream>>>(boxes, scores, out, out + 8 * TOPK_N * 5);
}

// Round 15
// 1413.949 us; speedup vs baseline: 1.0725x; 1.0725x over previous
//
#include <hip/hip_runtime.h>
#include <math.h>

// f32 I/O, f64 accumulation (bit-exact vs np-f64 ref — absmax 0.0 R4-R12).
// Workspace 96 MiB exactly: A(16,777,216 f32) + B(8,388,608 f32).
//
// R15: self-calibrating f64-MFMA conv. A 1-wave probe executes one
// mfma_f64_16x16x4 with lane-unique ASYMMETRIC values and determines which of
// 16 layout conventions (2 A-maps x 2 B-maps x 4 C/D-maps) the HW implements,
// writing the combo to d_out[0] (scratch; topk overwrites all of d_out last).
// Conv kernels read the flag and adapt gather indices + a layout-generic
// LDS-spill epilogue (correct under any combo). R14 failed because the f64
// fragment layout was assumed from the (bf16-verified) gfx950 tables; f64 was
// never in the verified set.

constexpr int TOPK_N = 200;

typedef double f64x4 __attribute__((ext_vector_type(4)));

// ---------------------------------------------------------------------------
// Layout probe: 1 block, 64 threads (one wave).
// A(16x4): af; B(4x16): bf. Candidate lane-maps:
//   Ai=0: lane = m+16k   Ai=1: lane = 4m+k
//   Bi=0: lane = 16k+n   Bi=1: lane = 4n+k
//   Ci=0: acc[r]=D[4z+r][lm]  Ci=1: D[lm][4z+r]  Ci=2: D[z+4r][lm]  Ci=3: D[lm][z+4r]
// combo = Ci*4 + Ai*2 + Bi, or -1 if none matches.
// ---------------------------------------------------------------------------
__launch_bounds__(64)
__global__ void mfma_probe_k(int* flag) {
    const int l = threadIdx.x;
    const int lm = l & 15, z = l >> 4;
    const double af = 1.0 + (double)l;
    const double bf = 2.0 + (double)(l * l);
    f64x4 acc = {0.0, 0.0, 0.0, 0.0};
    acc = __builtin_amdgcn_mfma_f64_16x16x4f64(af, bf, acc, 0, 0, 0);

    int found = -1;
    for (int Ci = 0; Ci < 4; ++Ci)
        for (int Ai = 0; Ai < 2; ++Ai)
            for (int Bi = 0; Bi < 2; ++Bi) {
                bool ok = true;
                for (int r = 0; r < 4; ++r) {
                    int m, n;
                    if (Ci == 0)      { m = 4 * z + r; n = lm; }
                    else if (Ci == 1) { m = lm;        n = 4 * z + r; }
                    else if (Ci == 2) { m = z + 4 * r; n = lm; }
                    else              { m = lm;        n = z + 4 * r; }
                    double e = 0.0;
                    for (int k = 0; k < 4; ++k) {
                        const int la = Ai ? (4 * m + k) : (m + 16 * k);
                        const int lb = Bi ? (4 * n + k) : (16 * k + n);
                        e += (1.0 + (double)la) * (2.0 + (double)(lb * lb));
                    }
                    if (fabs(acc[r] - e) > 0.5) { ok = false; break; }
                }
                const unsigned long long vote = __ballot(ok);
                if (vote == ~0ULL && found < 0) found = Ci * 4 + Ai * 2 + Bi;
            }
    if (l == 0) *flag = found;
}

// ---------------------------------------------------------------------------
// Self-adapting MFMA-f64 fused conv3x3(SAME)+bias+relu+maxpool2x2.
// Block = 256 thr = 4 waves; pooled 8x8 tile x 16 out-channels.
// Wave wv owns pooled [wv*16, wv*16+16) as 4 M-tiles of (4 pooled x 4 sib).
// ---------------------------------------------------------------------------
template <int CIN>
__launch_bounds__(256)
__global__ void conv_mfma(const float* __restrict__ in,
                          const float* __restrict__ wgt,
                          const float* __restrict__ bias,
                          float* __restrict__ out,
                          const int* __restrict__ flag_p,
                          int Hin, int Win, int Cout) {
    const int Hp = Hin >> 1, Wp = Win >> 1;
    const int coChunks = Cout >> 4;
    const int b  = blockIdx.z / coChunks;
    const int cz = blockIdx.z % coChunks;
    const int tid = threadIdx.x;
    const int lane = tid & 63;
    const int wv = tid >> 6;
    const int lm = lane & 15, z = lane >> 4;

    int combo = flag_p[0];
    if (combo < 0 || combo > 15) combo = 0;
    const int Ci = combo >> 2, Ai = (combo >> 1) & 1, Bi = combo & 1;

    // A-fragment lane role: supplies A[ma][ka]; B: supplies B[kb][nb].
    const int ma = Ai ? (lane >> 2) : lm;
    const int ka = Ai ? (lane & 3) : z;
    const int kb = Bi ? (lane & 3) : z;
    const int nb = Bi ? (lane >> 2) : lm;

    __shared__ double s_halo[4 * 324];        // 4 ci x 18x18, 10368 B
    __shared__ double s_wB[576];              // 36 taps x 16 co, 4608 B
    __shared__ float  s_pool[4][4][16][16];   // [wv][T][m][n], 16384 B

    // Per-step tap offsets (tap = 4*j + ka): ciL*324 + ky*18 + kx.
    int off[9];
#pragma unroll
    for (int j = 0; j < 9; ++j) {
        const int t = 4 * j + ka;
        const int ciL = t / 9, k = t - ciL * 9;
        const int ky = k / 3, kx = k - ky * 3;
        off[j] = ciL * 324 + ky * 18 + kx;
    }
    // A-row m=ma -> pooled r=ma>>2, sibling s=ma&3; tile T covers pooled T*4+r.
    int baseT[4];
    {
        const int s = ma & 3, dy = s >> 1, dx = s & 1, r = ma >> 2;
#pragma unroll
        for (int T = 0; T < 4; ++T) {
            const int p = wv * 16 + T * 4 + r;       // pooled 0..63 in 8x8 tile
            const int ey = 2 * (p >> 3) + dy, ex = 2 * (p & 7) + dx;
            baseT[T] = ey * 18 + ex;
        }
    }

    const size_t HW = (size_t)Hin * Win;
    const float* in_b = in + (size_t)b * CIN * HW;
    const int gy0 = blockIdx.y * 16, gx0 = blockIdx.x * 16;  // pre-pool origin

    f64x4 acc[4];
#pragma unroll
    for (int T = 0; T < 4; ++T) acc[T] = (f64x4){0.0, 0.0, 0.0, 0.0};

    for (int c0 = 0; c0 < CIN; c0 += 4) {
        __syncthreads();
        for (int s = 0; s < 6; ++s) {
            const int idx = tid + s * 256;
            if (idx < 1296) {
                const int ciL = idx / 324;
                const int rem = idx - ciL * 324;
                const int hy = rem / 18, hx = rem - hy * 18;
                const int iy = gy0 - 1 + hy, ix = gx0 - 1 + hx;
                double v = 0.0;
                if ((unsigned)iy < (unsigned)Hin && (unsigned)ix < (unsigned)Win)
                    v = (double)in_b[(size_t)(c0 + ciL) * HW + iy * Win + ix];
                s_halo[idx] = v;
            }
        }
        for (int s = 0; s < 3; ++s) {
            const int e = tid + s * 256;
            if (e < 576) {
                const int co = e & 15, t = e >> 4;
                const int ciL = t / 9, k = t - ciL * 9;
                s_wB[e] = (double)wgt[((cz * 16 + co) * CIN + c0 + ciL) * 9 + k];
            }
        }
        __syncthreads();

#pragma unroll
        for (int j = 0; j < 9; ++j) {
            const double bf = s_wB[(4 * j + kb) * 16 + nb];
#pragma unroll
            for (int T = 0; T < 4; ++T) {
                const double af = s_halo[baseT[T] + off[j]];
                acc[T] = __builtin_amdgcn_mfma_f64_16x16x4f64(af, bf, acc[T], 0, 0, 0);
            }
        }
    }

    // Layout-generic epilogue: spill relu'd f32 to s_pool by (m,n) per Ci.
    __syncthreads();
#pragma unroll
    for (int T = 0; T < 4; ++T) {
#pragma unroll
        for (int r = 0; r < 4; ++r) {
            int m, n;
            if (Ci == 0)      { m = 4 * z + r; n = lm; }
            else if (Ci == 1) { m = lm;        n = 4 * z + r; }
            else if (Ci == 2) { m = z + 4 * r; n = lm; }
            else              { m = lm;        n = z + 4 * r; }
            const float v =
                fmaxf((float)(acc[T][r] + (double)bias[cz * 16 + n]), 0.f);
            s_pool[wv][T][m][n] = v;
        }
    }
    __syncthreads();
    // Reduce pooling: pooled p = wvv*16 + T*4 + r; siblings m = 4r..4r+3.
    for (int e = tid; e < 1024; e += 256) {
        const int n  = e & 15;
        const int pr = e >> 4;                 // pooled 0..63
        const int wvv = pr >> 4, Tr = (pr >> 2) & 3, r = pr & 3;
        const float v0 = s_pool[wvv][Tr][4 * r + 0][n];
        const float v1 = s_pool[wvv][Tr][4 * r + 1][n];
        const float v2 = s_pool[wvv][Tr][4 * r + 2][n];
        const float v3 = s_pool[wvv][Tr][4 * r + 3][n];
        const float mx = fmaxf(fmaxf(v0, v1), fmaxf(v2, v3));
        const int py = blockIdx.y * 8 + (pr >> 3);
        const int px = blockIdx.x * 8 + (pr & 7);
        out[((size_t)(b * Cout + cz * 16 + n) * Hp + py) * Wp + px] = mx;
    }
}

// ---------------------------------------------------------------------------
// L1 vector conv (CIN=3) — R10's pipelined kernel, green since R10.
// ---------------------------------------------------------------------------
template <int CIN, int CI_BLK, int CO_BLK>
__launch_bounds__(256)
__global__ void conv_relu_pool_pipe(const float* __restrict__ in,
                                    const float* __restrict__ wgt,
                                    const float* __restrict__ bias,
                                    float* __restrict__ out,
                                    int Hin, int Win, int Cout) {
    constexpr int SPATIAL = 34 * 34;
    constexpr int SSLOT = (SPATIAL + 255) / 256;
    constexpr int NW = CI_BLK * 9 * CO_BLK;
    constexpr int NCHUNK = CIN / CI_BLK;
    const int Hp = Hin >> 1, Wp = Win >> 1;
    const int coChunks = Cout / CO_BLK;
    const int b  = blockIdx.z / coChunks;
    const int cz = blockIdx.z % coChunks;
    const int tid = threadIdx.x;
    const int tx = tid & 15, ty = tid >> 4;
    const int px = (blockIdx.x << 4) + tx;
    const int py = (blockIdx.y << 4) + ty;
    const int iy0 = (blockIdx.y << 5) - 1;
    const int ix0 = (blockIdx.x << 5) - 1;

    __shared__ float  s_in[2][CI_BLK * SPATIAL];
    __shared__ double s_w[2][NW];

    int soff[SSLOT];
#pragma unroll
    for (int s = 0; s < SSLOT; ++s) {
        const int cell = tid + s * 256;
        int g = -1;
        if (cell < SPATIAL) {
            const int ly = cell / 34, lx = cell - ly * 34;
            const int iy = iy0 + ly, ix = ix0 + lx;
            if ((unsigned)iy < (unsigned)Hin && (unsigned)ix < (unsigned)Win)
                g = iy * Win + ix;
        }
        soff[s] = g;
    }
    int wg = -1;
    if (tid < NW) {
        const int co   = tid & (CO_BLK - 1);
        const int rest = tid / CO_BLK;
        const int k    = rest % 9;
        const int ci   = rest / 9;
        wg = ((cz * CO_BLK + co) * CIN + ci) * 9 + k;
    }
    const size_t HW = (size_t)Hin * Win;
    const float* in_b = in + (size_t)b * CIN * HW;

    double acc[CO_BLK][4];
#pragma unroll
    for (int co = 0; co < CO_BLK; ++co)
#pragma unroll
        for (int p = 0; p < 4; ++p) acc[co][p] = 0.0;

    float rin[CI_BLK][SSLOT];
    float rw = 0.f;

#pragma unroll
    for (int ci = 0; ci < CI_BLK; ++ci) {
        const float* src = in_b + ci * HW;
#pragma unroll
        for (int s = 0; s < SSLOT; ++s) {
            const int cell = tid + s * 256;
            float v = 0.f;
            if (cell < SPATIAL) { const int g = soff[s]; if (g >= 0) v = src[g]; }
            rin[ci][s] = v;
        }
    }
    if (tid < NW) rw = wgt[wg];
#pragma unroll
    for (int ci = 0; ci < CI_BLK; ++ci)
#pragma unroll
        for (int s = 0; s < SSLOT; ++s) {
            const int cell = tid + s * 256;
            if (cell < SPATIAL) s_in[0][ci * SPATIAL + cell] = rin[ci][s];
        }
    if (tid < NW) s_w[0][tid] = (double)rw;
    __syncthreads();

    for (int c = 0; c < NCHUNK; ++c) {
        const int buf = c & 1;
        if (c + 1 < NCHUNK) {
            const int c0n = (c + 1) * CI_BLK;
#pragma unroll
            for (int ci = 0; ci < CI_BLK; ++ci) {
                const float* src = in_b + (c0n + ci) * HW;
#pragma unroll
                for (int s = 0; s < SSLOT; ++s) {
                    const int cell = tid + s * 256;
                    float v = 0.f;
                    if (cell < SPATIAL) { const int g = soff[s]; if (g >= 0) v = src[g]; }
                    rin[ci][s] = v;
                }
            }
            if (tid < NW) rw = wgt[wg + c0n * 9];
        }
#pragma unroll 1
        for (int ci = 0; ci < CI_BLK; ++ci) {
            const float* tile = &s_in[buf][ci * SPATIAL];
            double win[4][4];
#pragma unroll
            for (int iy = 0; iy < 4; ++iy) {
                float2 r0 = *(const float2*)&tile[(2 * ty + iy) * 34 + 2 * tx];
                float2 r1 = *(const float2*)&tile[(2 * ty + iy) * 34 + 2 * tx + 2];
                win[iy][0] = (double)r0.x; win[iy][1] = (double)r0.y;
                win[iy][2] = (double)r1.x; win[iy][3] = (double)r1.y;
            }
#pragma unroll
            for (int k = 0; k < 9; ++k) {
                const int ky = k / 3, kx = k % 3;
                const double* wp = &s_w[buf][(ci * 9 + k) * CO_BLK];
                double w[CO_BLK];
#pragma unroll
                for (int co = 0; co < CO_BLK; ++co) w[co] = wp[co];
#pragma unroll
                for (int p = 0; p < 4; ++p) {
                    const double v = win[(p >> 1) + ky][(p & 1) + kx];
#pragma unroll
                    for (int co = 0; co < CO_BLK; ++co)
                        acc[co][p] = fma(v, w[co], acc[co][p]);
                }
            }
        }
        if (c + 1 < NCHUNK) {
#pragma unroll
            for (int ci = 0; ci < CI_BLK; ++ci)
#pragma unroll
                for (int s = 0; s < SSLOT; ++s) {
                    const int cell = tid + s * 256;
                    if (cell < SPATIAL) s_in[buf ^ 1][ci * SPATIAL + cell] = rin[ci][s];
                }
            if (tid < NW) s_w[buf ^ 1][tid] = (double)rw;
            __syncthreads();
        }
    }

#pragma unroll
    for (int co = 0; co < CO_BLK; ++co) {
        const double bd = (double)bias[cz * CO_BLK + co];
        const float e0 = fmaxf((float)(acc[co][0] + bd), 0.f);
        const float e1 = fmaxf((float)(acc[co][1] + bd), 0.f);
        const float e2 = fmaxf((float)(acc[co][2] + bd), 0.f);
        const float e3 = fmaxf((float)(acc[co][3] + bd), 0.f);
        out[((size_t)(b * Cout + cz * CO_BLK + co) * Hp + py) * Wp + px] =
            fmaxf(fmaxf(e0, e1), fmaxf(e2, e3));
    }
}

// ---------------------------------------------------------------------------
// Head 1x1 conv (256->5, f64) + decode (f64) -> boxes/scores. 32 blocks.
// ---------------------------------------------------------------------------
__launch_bounds__(256)
__global__ void head_decode_k(const float* __restrict__ x4,
                              const float* __restrict__ wh,
                              const float* __restrict__ bh,
                              float* __restrict__ boxes,
                              float* __restrict__ scores) {
    __shared__ float s_wh[5 * 256];
    const int tid = threadIdx.x;
#pragma unroll
    for (int i = 0; i < 5; ++i) s_wh[i * 256 + tid] = wh[i * 256 + tid];
    __syncthreads();

    const int idx  = blockIdx.x * 256 + tid;
    const int b    = idx >> 10;
    const int cell = idx & 1023;
    const int gy = cell >> 5, gx = cell & 31;

    double a0 = (double)bh[0], a1 = (double)bh[1], a2 = (double)bh[2],
           a3 = (double)bh[3], a4 = (double)bh[4];
    const float* xp = x4 + b * 262144 + cell;
    for (int ci = 0; ci < 256; ++ci) {
        const double v = (double)xp[ci << 10];
        a0 = fma(v, (double)s_wh[0 * 256 + ci], a0);
        a1 = fma(v, (double)s_wh[1 * 256 + ci], a1);
        a2 = fma(v, (double)s_wh[2 * 256 + ci], a2);
        a3 = fma(v, (double)s_wh[3 * 256 + ci], a3);
        a4 = fma(v, (double)s_wh[4 * 256 + ci], a4);
    }
    const double obj = 1.0 / (1.0 + exp(-a0));
    const double txs = 1.0 / (1.0 + exp(-a1));
    const double tys = 1.0 / (1.0 + exp(-a2));
    const double bw  = exp(a3) * 16.0;
    const double bhh = exp(a4) * 16.0;
    const double cx  = gx * 16.0 + txs * 16.0;
    const double cy  = gy * 16.0 + tys * 16.0;
    float* bp = boxes + idx * 4;
    bp[0] = (float)fmin(fmax(cx - bw * 0.5, 0.0), 511.0);
    bp[1] = (float)fmin(fmax(cy - bhh * 0.5, 0.0), 511.0);
    bp[2] = (float)fmin(fmax(cx + bw * 0.5, 0.0), 511.0);
    bp[3] = (float)fmin(fmax(cy + bhh * 0.5, 0.0), 511.0);
    scores[idx] = (float)obj;
}

// ---------------------------------------------------------------------------
// Per-batch top-200 (bitonic, lax.top_k tie semantics) + greedy NMS + output.
// ---------------------------------------------------------------------------
__launch_bounds__(256)
__global__ void topk_nms_k(const float* __restrict__ boxes,
                           const float* __restrict__ scores,
                           float* __restrict__ out5,
                           float* __restrict__ keep_out) {
    const int b = blockIdx.x, tid = threadIdx.x;
    __shared__ unsigned long long key[1024];
    __shared__ float bx1[TOPK_N], by1[TOPK_N], bx2[TOPK_N], by2[TOPK_N];
    __shared__ float sv[TOPK_N], ar[TOPK_N];
    __shared__ int   kp[TOPK_N];

    for (int i = tid; i < 1024; i += 256) {
        float s = scores[b * 1024 + i];
        float m = (s >= 0.01f) ? s : -1.0f;
        unsigned u = __float_as_uint(m);
        u = (u & 0x80000000u) ? ~u : (u | 0x80000000u);
        key[i] = ((unsigned long long)u << 32) | (unsigned)(1023 - i);
    }
    __syncthreads();

    for (int k = 2; k <= 1024; k <<= 1) {
        for (int j = k >> 1; j > 0; j >>= 1) {
            for (int i = tid; i < 1024; i += 256) {
                int l = i ^ j;
                if (l > i) {
                    unsigned long long a = key[i], c = key[l];
                    bool desc = ((i & k) == 0);
                    bool sw = desc ? (a < c) : (a > c);
                    if (sw) { key[i] = c; key[l] = a; }
                }
            }
            __syncthreads();
        }
    }

    for (int i = tid; i < TOPK_N; i += 256) {
        unsigned long long kk = key[i];
        unsigned u = (unsigned)(kk >> 32);
        unsigned bits = (u & 0x80000000u) ? (u & 0x7FFFFFFFu) : ~u;
        float s = __uint_as_float(bits);
        int src = 1023 - (int)(kk & 0xFFFFFFFFu);
        const float4 bb = *(const float4*)(boxes + (b * 1024 + src) * 4);
        bx1[i] = bb.x; by1[i] = bb.y; bx2[i] = bb.z; by2[i] = bb.w;
        sv[i] = s;
        ar[i] = (bb.z - bb.x) * (bb.w - bb.y);
        kp[i] = (s >= 0.01f) ? 1 : 0;
    }
    __syncthreads();

    for (int i = 0; i < TOPK_N; ++i) {
        if (kp[i]) {
            const float X1 = bx1[i], Y1 = by1[i], X2 = bx2[i], Y2 = by2[i], A = ar[i];
            for (int j = tid; j < TOPK_N; j += 256) {
                if (j > i && kp[j]) {
                    float xx1 = fmaxf(X1, bx1[j]);
                    float yy1 = fmaxf(Y1, by1[j]);
                    float xx2 = fminf(X2, bx2[j]);
                    float yy2 = fminf(Y2, by2[j]);
                    float inter = fmaxf(xx2 - xx1, 0.f) * fmaxf(yy2 - yy1, 0.f);
                    float uni = A + ar[j] - inter;
                    float iou = inter / fmaxf(uni, 1e-6f);
                    if (iou > 0.5f) kp[j] = 0;
                }
            }
        }
        __syncthreads();
    }

    for (int i = tid; i < TOPK_N; i += 256) {
        float kf = kp[i] ? 1.f : 0.f;
        float s  = sv[i];
        float sc = (s >= 0.01f) ? s : 0.f;
        float* op = out5 + (b * TOPK_N + i) * 5;
        op[0] = bx1[i] * kf;
        op[1] = by1[i] * kf;
        op[2] = bx2[i] * kf;
        op[3] = by2[i] * kf;
        op[4] = sc * kf;
        keep_out[b * TOPK_N + i] = kf;
    }
}

extern "C" void kernel_launch(void* const* d_in, const int* in_sizes, int n_in,
                              void* d_out, int out_size, void* d_ws, size_t ws_size,
                              hipStream_t stream) {
    const float* images = (const float*)d_in[0];
    const float* w1 = (const float*)d_in[1];
    const float* b1 = (const float*)d_in[2];
    const float* w2 = (const float*)d_in[3];
    const float* b2 = (const float*)d_in[4];
    const float* w3 = (const float*)d_in[5];
    const float* b3 = (const float*)d_in[6];
    const float* w4 = (const float*)d_in[7];
    const float* b4 = (const float*)d_in[8];
    const float* wh = (const float*)d_in[9];
    const float* bh = (const float*)d_in[10];
    float* out = (float*)d_out;

    float* A    = (float*)d_ws;          // x1 [8,32,256,256] -> x3 [8,128,64,64]
    float* Bbuf = A + 16777216;          // x2 [8,64,128,128] -> x4 [8,256,32,32]
    float* boxes  = A + 8388608;         // dead x1 space after L4: 32768 floats
    float* scores = A + 8388608 + 32768; //  8192 floats
    int*   flag   = (int*)d_out;         // scratch; topk overwrites all of d_out

    // Layout probe (writes combo to d_out[0]).
    mfma_probe_k<<<1, 64, 0, stream>>>(flag);
    // L1: 3->32, vector path. 8192 blocks.
    conv_relu_pool_pipe<3, 3, 8><<<dim3(16, 16, 8 * 4), 256, 0, stream>>>(
        images, w1, b1, A, 512, 512, 32);
    // L2: 32->64 MFMA. pooled 128x128 -> 16x16 blocks, 4 co-chunks x 8 b.
    conv_mfma<32><<<dim3(16, 16, 8 * 4), 256, 0, stream>>>(
        A, w2, b2, Bbuf, flag, 256, 256, 64);
    // L3: 64->128 MFMA. 8x8 x (8 co-chunks x 8 b).
    conv_mfma<64><<<dim3(8, 8, 8 * 8), 256, 0, stream>>>(
        Bbuf, w3, b3, A, flag, 128, 128, 128);
    // L4: 128->256 MFMA. 4x4 x (16 co-chunks x 8 b).
    conv_mfma<128><<<dim3(4, 4, 8 * 16), 256, 0, stream>>>(
        A, w4, b4, Bbuf, flag, 64, 64, 256);
    // Head + decode: 32 blocks, coalesced
    head_decode_k<<<32, 256, 0, stream>>>(Bbuf, wh, bh, boxes, scores);
    // Top-k + NMS + output (overwrites the flag scratch in d_out)
    topk_nms_k<<<8, 256, 0, stream>>>(boxes, scores, out, out + 8 * TOPK_N * 5);
}